// Round 8
// baseline (834.559 us; speedup 1.0000x reference)
//
#include <hip/hip_runtime.h>

#define D 128
#define K_ORDER 6
#define NB_SHIFT 9           // bucket = dst >> 9 (512 nodes/bucket)
#define CPT 8                // edges per thread in binning passes

typedef __attribute__((ext_vector_type(8))) short short8;
typedef __attribute__((ext_vector_type(4))) float f32x4;
typedef __attribute__((ext_vector_type(4))) unsigned uint4v;

__device__ __forceinline__ float silu_f(float x) {
    return x / (1.0f + __expf(-x));
}

__device__ __forceinline__ unsigned pack_bf2(float lo, float hi) {
    unsigned ul = __float_as_uint(lo);
    unsigned uh = __float_as_uint(hi);
    ul = (ul + 0x7fffu + ((ul >> 16) & 1u)) >> 16;          // RNE
    uh = (uh + 0x7fffu + ((uh >> 16) & 1u)) & 0xffff0000u;  // RNE, keep high
    return uh | ul;
}

__device__ __forceinline__ unsigned short bf16_of(float f) {
    unsigned u = __float_as_uint(f);
    u = (u + 0x7fffu + ((u >> 16) & 1u)) >> 16;
    return (unsigned short)u;
}

// ---------------- CSR build (no global atomics on per-node arrays) ----------

__global__ __launch_bounds__(256) void bucket_hist_kernel(
        const int* __restrict__ dst, int* __restrict__ bucket_cnt, int e, int nb) {
    __shared__ int hist[256];
    for (int i = threadIdx.x; i < 256; i += 256) hist[i] = 0;
    __syncthreads();
    int i0 = blockIdx.x * (256 * CPT) + threadIdx.x;
    #pragma unroll
    for (int k = 0; k < CPT; ++k) {
        int idx = i0 + k * 256;
        if (idx < e) atomicAdd(&hist[dst[idx] >> NB_SHIFT], 1);
    }
    __syncthreads();
    for (int i = threadIdx.x; i < nb; i += 256) {
        int h = hist[i];
        if (h) atomicAdd(&bucket_cnt[i], h);
    }
}

__global__ __launch_bounds__(256) void scan_buckets_kernel(
        const int* __restrict__ bucket_cnt, int* __restrict__ bucket_base,
        int* __restrict__ bin_cur, int nb) {
    __shared__ int lds[256];
    int v = (threadIdx.x < (unsigned)nb) ? bucket_cnt[threadIdx.x] : 0;
    lds[threadIdx.x] = v;
    __syncthreads();
    #pragma unroll
    for (int off = 1; off < 256; off <<= 1) {
        int t = (threadIdx.x >= (unsigned)off) ? lds[threadIdx.x - off] : 0;
        __syncthreads();
        lds[threadIdx.x] += t;
        __syncthreads();
    }
    if (threadIdx.x < (unsigned)nb) {
        int b = lds[threadIdx.x] - v;
        bucket_base[threadIdx.x] = b;
        bin_cur[threadIdx.x] = b;
    }
}

__global__ __launch_bounds__(256) void bin_edges_kernel(
        const int* __restrict__ src, const int* __restrict__ dst,
        int* __restrict__ bin_cur, unsigned* __restrict__ binned, int e, int nb) {
    __shared__ int hist[256];
    __shared__ int base[256];
    for (int i = threadIdx.x; i < 256; i += 256) hist[i] = 0;
    __syncthreads();

    int e0 = blockIdx.x * (256 * CPT) + threadIdx.x;
    int myb[CPT], myoff[CPT];
    unsigned mypk[CPT];
    #pragma unroll
    for (int k = 0; k < CPT; ++k) {
        int idx = e0 + k * 256;
        bool ok = idx < e;
        int d = ok ? dst[idx] : 0;
        int s = ok ? src[idx] : 0;
        int b = d >> NB_SHIFT;
        int off = ok ? atomicAdd(&hist[b], 1) : 0;
        myb[k] = b; myoff[k] = off;
        mypk[k] = ((unsigned)s << NB_SHIFT) | (unsigned)(d & ((1 << NB_SHIFT) - 1));
    }
    __syncthreads();
    for (int i = threadIdx.x; i < nb; i += 256) {
        int h = hist[i];
        base[i] = h ? atomicAdd(&bin_cur[i], h) : 0;
    }
    __syncthreads();
    #pragma unroll
    for (int k = 0; k < CPT; ++k) {
        int idx = e0 + k * 256;
        if (idx < e)
            binned[(size_t)base[myb[k]] + myoff[k]] = mypk[k];
    }
}

__global__ __launch_bounds__(512) void bucket_csr_kernel(
        const unsigned* __restrict__ binned, const int* __restrict__ bucket_base,
        int* __restrict__ row_ptr, int* __restrict__ ssrc, int n, int e, int nb) {
    __shared__ int hist[512];
    __shared__ int pfx[512];
    const int b = blockIdx.x;
    const int node0 = b << NB_SHIFT;
    const int beg = bucket_base[b];
    const int end = (b + 1 < nb) ? bucket_base[b + 1] : e;

    hist[threadIdx.x] = 0;
    __syncthreads();
    for (int j = beg + (int)threadIdx.x; j < end; j += 512)
        atomicAdd(&hist[binned[j] & 511u], 1);
    __syncthreads();

    int v = hist[threadIdx.x];
    pfx[threadIdx.x] = v;
    __syncthreads();
    #pragma unroll
    for (int off = 1; off < 512; off <<= 1) {
        int t = (threadIdx.x >= (unsigned)off) ? pfx[threadIdx.x - off] : 0;
        __syncthreads();
        pfx[threadIdx.x] += t;
        __syncthreads();
    }
    int excl = pfx[threadIdx.x] - v;

    int node = node0 + (int)threadIdx.x;
    if (node < n) row_ptr[node] = beg + excl;
    if (b == nb - 1 && threadIdx.x == 0) row_ptr[n] = e;
    __syncthreads();

    hist[threadIdx.x] = 0;     // reuse as per-node cursor
    pfx[threadIdx.x] = excl;   // exclusive prefix
    __syncthreads();

    for (int j = beg + (int)threadIdx.x; j < end; j += 512) {
        unsigned p = binned[j];
        int dl = (int)(p & 511u);
        int pos = beg + pfx[dl] + atomicAdd(&hist[dl], 1);
        ssrc[pos] = (int)(p >> NB_SHIFT);
    }
}

// ---------------- degree-sorted permutation (counting sort by degree) -------

__global__ __launch_bounds__(512) void deg_hist_kernel(
        const int* __restrict__ row_ptr, int* __restrict__ dhist, int n) {
    __shared__ int h[512];
    h[threadIdx.x] = 0;
    __syncthreads();
    int i = blockIdx.x * 512 + threadIdx.x;
    if (i < n) {
        int d = row_ptr[i + 1] - row_ptr[i];
        if (d > 511) d = 511;
        atomicAdd(&h[d], 1);
    }
    __syncthreads();
    int v = h[threadIdx.x];
    if (v) atomicAdd(&dhist[threadIdx.x], v);
}

__global__ __launch_bounds__(512) void deg_scan_kernel(
        const int* __restrict__ dhist, int* __restrict__ dcur) {
    __shared__ int lds[512];
    int v = dhist[threadIdx.x];
    lds[threadIdx.x] = v;
    __syncthreads();
    #pragma unroll
    for (int off = 1; off < 512; off <<= 1) {
        int t = (threadIdx.x >= (unsigned)off) ? lds[threadIdx.x - off] : 0;
        __syncthreads();
        lds[threadIdx.x] += t;
        __syncthreads();
    }
    dcur[threadIdx.x] = lds[threadIdx.x] - v;   // exclusive base
}

__global__ __launch_bounds__(512) void deg_scatter_kernel(
        const int* __restrict__ row_ptr, int* __restrict__ dcur,
        int* __restrict__ perm, int n) {
    int i = blockIdx.x * 512 + threadIdx.x;
    if (i < n) {
        int d = row_ptr[i + 1] - row_ptr[i];
        if (d > 511) d = 511;
        int pos = atomicAdd(&dcur[d], 1);
        perm[pos] = i;
    }
}

// ---------------- weight pre-transpose: W (f32 row-major) -> W^T bf16 -------
__global__ __launch_bounds__(256) void transpose_w_kernel(
        const float* __restrict__ W0, const float* __restrict__ W1,
        const float* __restrict__ W2, unsigned short* __restrict__ Wt) {
    int i = blockIdx.x * 256 + threadIdx.x;     // 0 .. 3*16384-1
    int w = i >> 14;
    int r = i & 16383;
    int k = r >> 7, c = r & 127;
    const float* W = (w == 0) ? W0 : ((w == 1) ? W1 : W2);
    Wt[(size_t)w * 16384 + c * 128 + k] = bf16_of(W[r]);
}

// ---------------- MFMA GEMM: [nrows x 128] @ [128 x 128], no LDS -----------
// B-fragments read straight from global bf16 W^T (32 KB, L1-resident).
// ALAY: 0 = fp32 A, 1 = bf16 A.  OLAY: 0 = bf16 out, 1 = fp32 out.
template <int ALAY, bool SILU, int OLAY>
__global__ __launch_bounds__(256) void gemm_mfma_kernel(
        const void* __restrict__ Ap, const unsigned short* __restrict__ Wt,
        const float* __restrict__ bias, void* __restrict__ outp, int nrows) {
    const int wave = threadIdx.x >> 6;
    const int lane = threadIdx.x & 63;
    const int lhi = lane >> 4;
    const int llo = lane & 15;

    const int rbase = blockIdx.x * 128 + wave * 32;

    f32x4 acc[2][8] = {};

    #pragma unroll
    for (int ks = 0; ks < 4; ++ks) {
        const int k0 = ks * 32 + lhi * 8;
        short8 afrag[2];
        #pragma unroll
        for (int rt = 0; rt < 2; ++rt) {
            int r = rbase + rt * 16 + llo;
            if (r < nrows) {
                if (ALAY == 0) {
                    const float* ap = (const float*)Ap + (size_t)r * 128 + k0;
                    float4 f0 = *(const float4*)ap;
                    float4 f1 = *(const float4*)(ap + 4);
                    union { unsigned u[4]; short8 s; } cvt;
                    cvt.u[0] = pack_bf2(f0.x, f0.y);
                    cvt.u[1] = pack_bf2(f0.z, f0.w);
                    cvt.u[2] = pack_bf2(f1.x, f1.y);
                    cvt.u[3] = pack_bf2(f1.z, f1.w);
                    afrag[rt] = cvt.s;
                } else {
                    afrag[rt] = *(const short8*)((const unsigned short*)Ap + (size_t)r * 128 + k0);
                }
            } else {
                afrag[rt] = short8{0, 0, 0, 0, 0, 0, 0, 0};
            }
        }
        #pragma unroll
        for (int ct = 0; ct < 8; ++ct) {
            short8 bfrag = *(const short8*)(Wt + (size_t)(ct * 16 + llo) * 128 + k0);
            acc[0][ct] = __builtin_amdgcn_mfma_f32_16x16x32_bf16(afrag[0], bfrag, acc[0][ct], 0, 0, 0);
            acc[1][ct] = __builtin_amdgcn_mfma_f32_16x16x32_bf16(afrag[1], bfrag, acc[1][ct], 0, 0, 0);
        }
    }

    float bv[8];
    #pragma unroll
    for (int ct = 0; ct < 8; ++ct) bv[ct] = bias[ct * 16 + llo];

    #pragma unroll
    for (int rt = 0; rt < 2; ++rt) {
        int rb = rbase + rt * 16 + lhi * 4;
        #pragma unroll
        for (int reg = 0; reg < 4; ++reg) {
            int r = rb + reg;
            if (r >= nrows) continue;
            if (OLAY == 1) {
                float* orow = (float*)outp + (size_t)r * 128;
                #pragma unroll
                for (int ct = 0; ct < 8; ++ct) {
                    float v = acc[rt][ct][reg] + bv[ct];
                    if (SILU) v = silu_f(v);
                    orow[ct * 16 + llo] = v;
                }
            } else {
                unsigned short* orow = (unsigned short*)outp + (size_t)r * 128;
                #pragma unroll
                for (int ct = 0; ct < 8; ++ct) {
                    float v = acc[rt][ct][reg] + bv[ct];
                    if (SILU) v = silu_f(v);
                    orow[ct * 16 + llo] = bf16_of(v);
                }
            }
        }
    }
}

// ---------------- Horner diffusion step, row-major bf16, deg-sorted ---------
// u_next = x + (inv_i / deg) * (A u). 16 lanes per row, uint4 (16 B = 8 feats)
// per lane. Rows processed in degree-sorted order (perm) so all rows in a
// wave/block have ~equal degree -> no straggler slots. fp32 accumulate.

#define ACC8(v)                                          \
    do {                                                 \
        a0 += __uint_as_float((v).x << 16);              \
        a1 += __uint_as_float((v).x & 0xffff0000u);      \
        a2 += __uint_as_float((v).y << 16);              \
        a3 += __uint_as_float((v).y & 0xffff0000u);      \
        a4 += __uint_as_float((v).z << 16);              \
        a5 += __uint_as_float((v).z & 0xffff0000u);      \
        a6 += __uint_as_float((v).w << 16);              \
        a7 += __uint_as_float((v).w & 0xffff0000u);      \
    } while (0)

__global__ __launch_bounds__(256) void horner_bf_kernel(
        const uint4v* __restrict__ u, const uint4v* __restrict__ xb,
        uint4v* __restrict__ u_next,
        const int* __restrict__ row_ptr, const int* __restrict__ ssrc,
        const int* __restrict__ perm,
        float inv_i, int nrows) {
    const int lt = threadIdx.x & 15;                 // lane within row group
    const int gid = blockIdx.x * 16 + (threadIdx.x >> 4);
    if (gid >= nrows) return;
    const int row = perm[gid];

    const int beg = row_ptr[row];
    const int end = row_ptr[row + 1];
    const int deg = end - beg;

    float a0 = 0.f, a1 = 0.f, a2 = 0.f, a3 = 0.f,
          a4 = 0.f, a5 = 0.f, a6 = 0.f, a7 = 0.f;

    int j = beg;
    for (; j + 7 < end; j += 8) {
        int s0 = ssrc[j + 0], s1 = ssrc[j + 1], s2 = ssrc[j + 2], s3 = ssrc[j + 3];
        int s4 = ssrc[j + 4], s5 = ssrc[j + 5], s6 = ssrc[j + 6], s7 = ssrc[j + 7];
        uint4v t0 = u[(size_t)s0 * 16 + lt];
        uint4v t1 = u[(size_t)s1 * 16 + lt];
        uint4v t2 = u[(size_t)s2 * 16 + lt];
        uint4v t3 = u[(size_t)s3 * 16 + lt];
        uint4v t4 = u[(size_t)s4 * 16 + lt];
        uint4v t5 = u[(size_t)s5 * 16 + lt];
        uint4v t6 = u[(size_t)s6 * 16 + lt];
        uint4v t7 = u[(size_t)s7 * 16 + lt];
        ACC8(t0); ACC8(t1); ACC8(t2); ACC8(t3);
        ACC8(t4); ACC8(t5); ACC8(t6); ACC8(t7);
    }
    for (; j + 3 < end; j += 4) {
        int s0 = ssrc[j + 0], s1 = ssrc[j + 1], s2 = ssrc[j + 2], s3 = ssrc[j + 3];
        uint4v t0 = u[(size_t)s0 * 16 + lt];
        uint4v t1 = u[(size_t)s1 * 16 + lt];
        uint4v t2 = u[(size_t)s2 * 16 + lt];
        uint4v t3 = u[(size_t)s3 * 16 + lt];
        ACC8(t0); ACC8(t1); ACC8(t2); ACC8(t3);
    }
    for (; j < end; ++j) {
        uint4v t0 = u[(size_t)ssrc[j] * 16 + lt];
        ACC8(t0);
    }

    const float scale = inv_i / (float)(deg > 1 ? deg : 1);
    const size_t o = (size_t)row * 16 + lt;
    uint4v xv = xb[o];
    float r0 = fmaf(a0, scale, __uint_as_float(xv.x << 16));
    float r1 = fmaf(a1, scale, __uint_as_float(xv.x & 0xffff0000u));
    float r2 = fmaf(a2, scale, __uint_as_float(xv.y << 16));
    float r3 = fmaf(a3, scale, __uint_as_float(xv.y & 0xffff0000u));
    float r4 = fmaf(a4, scale, __uint_as_float(xv.z << 16));
    float r5 = fmaf(a5, scale, __uint_as_float(xv.z & 0xffff0000u));
    float r6 = fmaf(a6, scale, __uint_as_float(xv.w << 16));
    float r7 = fmaf(a7, scale, __uint_as_float(xv.w & 0xffff0000u));
    uint4v ov;
    ov.x = pack_bf2(r0, r1);
    ov.y = pack_bf2(r2, r3);
    ov.z = pack_bf2(r4, r5);
    ov.w = pack_bf2(r6, r7);
    __builtin_nontemporal_store(ov, u_next + o);
}

// ---------------- launch ----------------

extern "C" void kernel_launch(void* const* d_in, const int* in_sizes, int n_in,
                              void* d_out, int out_size, void* d_ws, size_t ws_size,
                              hipStream_t stream) {
    const float* h      = (const float*)d_in[0];
    const int*   eidx   = (const int*)d_in[1];
    const float* W_in   = (const float*)d_in[2];
    const float* b_in   = (const float*)d_in[3];
    const float* W1     = (const float*)d_in[4];
    const float* b1     = (const float*)d_in[5];
    const float* W2     = (const float*)d_in[6];
    const float* b2     = (const float*)d_in[7];
    float* out = (float*)d_out;

    const int N = in_sizes[0] / D;      // 100000
    const int E = in_sizes[1] / 2;      // 1600000
    const int NB = (N + (1 << NB_SHIFT) - 1) >> NB_SHIFT;   // 196 buckets

    const int* e_src = eidx;
    const int* e_dst = eidx + E;

    // workspace layout
    unsigned short* Xb = (unsigned short*)d_ws;         // N*128 shorts (row-major bf16)
    unsigned short* U0 = Xb + (size_t)N * 128;          // N*128 shorts
    unsigned short* U1 = U0 + (size_t)N * 128;          // N*128 shorts
    unsigned short* Wt = U1 + (size_t)N * 128;          // 3*16384 shorts (bf16 W^T x3)
    unsigned* binned   = (unsigned*)(Wt + 3 * 16384);   // E
    int* ssrc        = (int*)(binned + E);              // E
    int* row_ptr     = ssrc + E;                        // N+1
    int* bucket_cnt  = row_ptr + N + 1;                 // 256
    int* dhist       = bucket_cnt + 256;                // 512
    int* dcur        = dhist + 512;                     // 512
    int* bucket_base = dcur + 512;                      // 256
    int* bin_cur     = bucket_base + 256;               // 256
    int* perm        = bin_cur + 256;                   // N

    // zero bucket_cnt + dhist (adjacent)
    hipMemsetAsync(bucket_cnt, 0, (256 + 512) * sizeof(int), stream);

    const int eb = (E + 256 * CPT - 1) / (256 * CPT);
    bucket_hist_kernel<<<eb, 256, 0, stream>>>(e_dst, bucket_cnt, E, NB);
    scan_buckets_kernel<<<1, 256, 0, stream>>>(bucket_cnt, bucket_base, bin_cur, NB);
    bin_edges_kernel<<<eb, 256, 0, stream>>>(e_src, e_dst, bin_cur, binned, E, NB);
    bucket_csr_kernel<<<NB, 512, 0, stream>>>(binned, bucket_base, row_ptr, ssrc, N, E, NB);

    // degree-sorted permutation
    const int nrb = (N + 511) / 512;
    deg_hist_kernel<<<nrb, 512, 0, stream>>>(row_ptr, dhist, N);
    deg_scan_kernel<<<1, 512, 0, stream>>>(dhist, dcur);
    deg_scatter_kernel<<<nrb, 512, 0, stream>>>(row_ptr, dcur, perm, N);

    // weight pre-transpose (bf16 W^T for all three GEMMs)
    transpose_w_kernel<<<192, 256, 0, stream>>>(W_in, W1, W2, Wt);

    const int gb = (N + 127) / 128;
    // Xb = bf16(silu(h @ W_in + b_in))
    gemm_mfma_kernel<0, true, 0><<<gb, 256, 0, stream>>>(h, Wt, b_in, Xb, N);

    // Horner: u = x; for i = K..1: u = x + (A u)/i   (bf16 state)
    const int db = (N + 15) / 16;
    const uint4v* Xv = (const uint4v*)Xb;
    uint4v* U0v = (uint4v*)U0;
    uint4v* U1v = (uint4v*)U1;
    horner_bf_kernel<<<db, 256, 0, stream>>>(Xv, Xv, U0v, row_ptr, ssrc, perm, 1.0f / 6.0f, N);
    horner_bf_kernel<<<db, 256, 0, stream>>>(U0v, Xv, U1v, row_ptr, ssrc, perm, 1.0f / 5.0f, N);
    horner_bf_kernel<<<db, 256, 0, stream>>>(U1v, Xv, U0v, row_ptr, ssrc, perm, 1.0f / 4.0f, N);
    horner_bf_kernel<<<db, 256, 0, stream>>>(U0v, Xv, U1v, row_ptr, ssrc, perm, 1.0f / 3.0f, N);
    horner_bf_kernel<<<db, 256, 0, stream>>>(U1v, Xv, U0v, row_ptr, ssrc, perm, 1.0f / 2.0f, N);
    horner_bf_kernel<<<db, 256, 0, stream>>>(U0v, Xv, U1v, row_ptr, ssrc, perm, 1.0f, N);
    // final diffusion result: U1 (bf16)

    // U0 = bf16(silu(U1 @ W1 + b1))
    gemm_mfma_kernel<1, true, 0><<<gb, 256, 0, stream>>>(U1, Wt + 16384, b1, U0, N);
    // out = U0 @ W2 + b2  (fp32)
    gemm_mfma_kernel<1, false, 1><<<gb, 256, 0, stream>>>(U0, Wt + 2 * 16384, b2, out, N);
}

// Round 9
// 561.862 us; speedup vs baseline: 1.4853x; 1.4853x over previous
//
#include <hip/hip_runtime.h>

#define D 128
#define K_ORDER 6
#define NB_SHIFT 9           // bucket = dst >> 9 (512 nodes/bucket)
#define CPT 8                // edges per thread in binning passes

typedef __attribute__((ext_vector_type(8))) short short8;
typedef __attribute__((ext_vector_type(4))) float f32x4;
typedef __attribute__((ext_vector_type(4))) unsigned uint4v;

__device__ __forceinline__ float silu_f(float x) {
    return x / (1.0f + __expf(-x));
}

__device__ __forceinline__ unsigned pack_bf2(float lo, float hi) {
    unsigned ul = __float_as_uint(lo);
    unsigned uh = __float_as_uint(hi);
    ul = (ul + 0x7fffu + ((ul >> 16) & 1u)) >> 16;          // RNE
    uh = (uh + 0x7fffu + ((uh >> 16) & 1u)) & 0xffff0000u;  // RNE, keep high
    return uh | ul;
}

__device__ __forceinline__ unsigned short bf16_of(float f) {
    unsigned u = __float_as_uint(f);
    u = (u + 0x7fffu + ((u >> 16) & 1u)) >> 16;
    return (unsigned short)u;
}

// ---------------- generic hierarchical scan (3 passes) ----------------

__global__ __launch_bounds__(512) void scan_pass1_kernel(
        const int* __restrict__ in, int* __restrict__ out,
        int* __restrict__ partials, int n) {
    __shared__ int lds[512];
    int i = blockIdx.x * 512 + threadIdx.x;
    int v = (i < n) ? in[i] : 0;
    lds[threadIdx.x] = v;
    __syncthreads();
    #pragma unroll
    for (int off = 1; off < 512; off <<= 1) {
        int t = (threadIdx.x >= (unsigned)off) ? lds[threadIdx.x - off] : 0;
        __syncthreads();
        lds[threadIdx.x] += t;
        __syncthreads();
    }
    if (i < n) out[i] = lds[threadIdx.x] - v;   // exclusive
    if (threadIdx.x == 511) partials[blockIdx.x] = lds[511];
}

__global__ __launch_bounds__(256) void scan_pass2_kernel(int* __restrict__ partials, int np) {
    __shared__ int lds[256];
    int v = (threadIdx.x < (unsigned)np) ? partials[threadIdx.x] : 0;
    lds[threadIdx.x] = v;
    __syncthreads();
    #pragma unroll
    for (int off = 1; off < 256; off <<= 1) {
        int t = (threadIdx.x >= (unsigned)off) ? lds[threadIdx.x - off] : 0;
        __syncthreads();
        lds[threadIdx.x] += t;
        __syncthreads();
    }
    if (threadIdx.x < (unsigned)np) partials[threadIdx.x] = lds[threadIdx.x] - v;
}

__global__ __launch_bounds__(512) void scan_pass3_kernel(
        int* __restrict__ data, const int* __restrict__ partials, int n) {
    int i = blockIdx.x * 512 + threadIdx.x;
    if (i < n) data[i] += partials[blockIdx.x];
}

// ---------------- CSR build (no global atomics on per-node arrays) ----------

__global__ __launch_bounds__(256) void bucket_hist_kernel(
        const int* __restrict__ dst, int* __restrict__ bucket_cnt, int e, int nb) {
    __shared__ int hist[256];
    for (int i = threadIdx.x; i < 256; i += 256) hist[i] = 0;
    __syncthreads();
    int i0 = blockIdx.x * (256 * CPT) + threadIdx.x;
    #pragma unroll
    for (int k = 0; k < CPT; ++k) {
        int idx = i0 + k * 256;
        if (idx < e) atomicAdd(&hist[dst[idx] >> NB_SHIFT], 1);
    }
    __syncthreads();
    for (int i = threadIdx.x; i < nb; i += 256) {
        int h = hist[i];
        if (h) atomicAdd(&bucket_cnt[i], h);
    }
}

__global__ __launch_bounds__(256) void scan_buckets_kernel(
        const int* __restrict__ bucket_cnt, int* __restrict__ bucket_base,
        int* __restrict__ bin_cur, int nb) {
    __shared__ int lds[256];
    int v = (threadIdx.x < (unsigned)nb) ? bucket_cnt[threadIdx.x] : 0;
    lds[threadIdx.x] = v;
    __syncthreads();
    #pragma unroll
    for (int off = 1; off < 256; off <<= 1) {
        int t = (threadIdx.x >= (unsigned)off) ? lds[threadIdx.x - off] : 0;
        __syncthreads();
        lds[threadIdx.x] += t;
        __syncthreads();
    }
    if (threadIdx.x < (unsigned)nb) {
        int b = lds[threadIdx.x] - v;
        bucket_base[threadIdx.x] = b;
        bin_cur[threadIdx.x] = b;
    }
}

__global__ __launch_bounds__(256) void bin_edges_kernel(
        const int* __restrict__ src, const int* __restrict__ dst,
        int* __restrict__ bin_cur, unsigned* __restrict__ binned, int e, int nb) {
    __shared__ int hist[256];
    __shared__ int base[256];
    for (int i = threadIdx.x; i < 256; i += 256) hist[i] = 0;
    __syncthreads();

    int e0 = blockIdx.x * (256 * CPT) + threadIdx.x;
    int myb[CPT], myoff[CPT];
    unsigned mypk[CPT];
    #pragma unroll
    for (int k = 0; k < CPT; ++k) {
        int idx = e0 + k * 256;
        bool ok = idx < e;
        int d = ok ? dst[idx] : 0;
        int s = ok ? src[idx] : 0;
        int b = d >> NB_SHIFT;
        int off = ok ? atomicAdd(&hist[b], 1) : 0;
        myb[k] = b; myoff[k] = off;
        mypk[k] = ((unsigned)s << NB_SHIFT) | (unsigned)(d & ((1 << NB_SHIFT) - 1));
    }
    __syncthreads();
    for (int i = threadIdx.x; i < nb; i += 256) {
        int h = hist[i];
        base[i] = h ? atomicAdd(&bin_cur[i], h) : 0;
    }
    __syncthreads();
    #pragma unroll
    for (int k = 0; k < CPT; ++k) {
        int idx = e0 + k * 256;
        if (idx < e)
            binned[(size_t)base[myb[k]] + myoff[k]] = mypk[k];
    }
}

__global__ __launch_bounds__(512) void bucket_csr_kernel(
        const unsigned* __restrict__ binned, const int* __restrict__ bucket_base,
        int* __restrict__ row_ptr, int* __restrict__ ssrc, int n, int e, int nb) {
    __shared__ int hist[512];
    __shared__ int pfx[512];
    const int b = blockIdx.x;
    const int node0 = b << NB_SHIFT;
    const int beg = bucket_base[b];
    const int end = (b + 1 < nb) ? bucket_base[b + 1] : e;

    hist[threadIdx.x] = 0;
    __syncthreads();
    for (int j = beg + (int)threadIdx.x; j < end; j += 512)
        atomicAdd(&hist[binned[j] & 511u], 1);
    __syncthreads();

    int v = hist[threadIdx.x];
    pfx[threadIdx.x] = v;
    __syncthreads();
    #pragma unroll
    for (int off = 1; off < 512; off <<= 1) {
        int t = (threadIdx.x >= (unsigned)off) ? pfx[threadIdx.x - off] : 0;
        __syncthreads();
        pfx[threadIdx.x] += t;
        __syncthreads();
    }
    int excl = pfx[threadIdx.x] - v;

    int node = node0 + (int)threadIdx.x;
    if (node < n) row_ptr[node] = beg + excl;
    if (b == nb - 1 && threadIdx.x == 0) row_ptr[n] = e;
    __syncthreads();

    hist[threadIdx.x] = 0;     // reuse as per-node cursor
    pfx[threadIdx.x] = excl;   // exclusive prefix
    __syncthreads();

    for (int j = beg + (int)threadIdx.x; j < end; j += 512) {
        unsigned p = binned[j];
        int dl = (int)(p & 511u);
        int pos = beg + pfx[dl] + atomicAdd(&hist[dl], 1);
        ssrc[pos] = (int)(p >> NB_SHIFT);
    }
}

// ---------------- degree-sorted permutation, contention-free ----------------
// cnt is degree-major: cnt[d * nrb + b] = # rows of (clamped) degree d in block b.

__global__ __launch_bounds__(512) void deg_cnt_kernel(
        const int* __restrict__ row_ptr, int* __restrict__ cnt, int n, int nrb) {
    __shared__ int h[512];
    h[threadIdx.x] = 0;
    __syncthreads();
    int i = blockIdx.x * 512 + threadIdx.x;
    if (i < n) {
        int d = row_ptr[i + 1] - row_ptr[i];
        if (d > 511) d = 511;
        atomicAdd(&h[d], 1);
    }
    __syncthreads();
    cnt[(size_t)threadIdx.x * nrb + blockIdx.x] = h[threadIdx.x];
}

__global__ __launch_bounds__(512) void deg_scatter_kernel(
        const int* __restrict__ row_ptr, const int* __restrict__ cnt_scan,
        int* __restrict__ perm, int n, int nrb) {
    __shared__ int cur[512];
    cur[threadIdx.x] = 0;
    __syncthreads();
    int i = blockIdx.x * 512 + threadIdx.x;
    if (i < n) {
        int d = row_ptr[i + 1] - row_ptr[i];
        if (d > 511) d = 511;
        int local = atomicAdd(&cur[d], 1);          // LDS cursor only
        int pos = cnt_scan[(size_t)d * nrb + blockIdx.x] + local;
        perm[pos] = i;
    }
}

// ---------------- weight pre-transpose: W (f32 row-major) -> W^T bf16 -------
__global__ __launch_bounds__(256) void transpose_w_kernel(
        const float* __restrict__ W0, const float* __restrict__ W1,
        const float* __restrict__ W2, unsigned short* __restrict__ Wt) {
    int i = blockIdx.x * 256 + threadIdx.x;     // 0 .. 3*16384-1
    int w = i >> 14;
    int r = i & 16383;
    int k = r >> 7, c = r & 127;
    const float* W = (w == 0) ? W0 : ((w == 1) ? W1 : W2);
    Wt[(size_t)w * 16384 + c * 128 + k] = bf16_of(W[r]);
}

// ---------------- MFMA GEMM: [nrows x 128] @ [128 x 128], no LDS -----------
// ALAY: 0 = fp32 A, 1 = bf16 A.  OLAY: 0 = bf16 out, 1 = fp32 out.
template <int ALAY, bool SILU, int OLAY>
__global__ __launch_bounds__(256) void gemm_mfma_kernel(
        const void* __restrict__ Ap, const unsigned short* __restrict__ Wt,
        const float* __restrict__ bias, void* __restrict__ outp, int nrows) {
    const int wave = threadIdx.x >> 6;
    const int lane = threadIdx.x & 63;
    const int lhi = lane >> 4;
    const int llo = lane & 15;

    const int rbase = blockIdx.x * 128 + wave * 32;

    f32x4 acc[2][8] = {};

    #pragma unroll
    for (int ks = 0; ks < 4; ++ks) {
        const int k0 = ks * 32 + lhi * 8;
        short8 afrag[2];
        #pragma unroll
        for (int rt = 0; rt < 2; ++rt) {
            int r = rbase + rt * 16 + llo;
            if (r < nrows) {
                if (ALAY == 0) {
                    const float* ap = (const float*)Ap + (size_t)r * 128 + k0;
                    float4 f0 = *(const float4*)ap;
                    float4 f1 = *(const float4*)(ap + 4);
                    union { unsigned u[4]; short8 s; } cvt;
                    cvt.u[0] = pack_bf2(f0.x, f0.y);
                    cvt.u[1] = pack_bf2(f0.z, f0.w);
                    cvt.u[2] = pack_bf2(f1.x, f1.y);
                    cvt.u[3] = pack_bf2(f1.z, f1.w);
                    afrag[rt] = cvt.s;
                } else {
                    afrag[rt] = *(const short8*)((const unsigned short*)Ap + (size_t)r * 128 + k0);
                }
            } else {
                afrag[rt] = short8{0, 0, 0, 0, 0, 0, 0, 0};
            }
        }
        #pragma unroll
        for (int ct = 0; ct < 8; ++ct) {
            short8 bfrag = *(const short8*)(Wt + (size_t)(ct * 16 + llo) * 128 + k0);
            acc[0][ct] = __builtin_amdgcn_mfma_f32_16x16x32_bf16(afrag[0], bfrag, acc[0][ct], 0, 0, 0);
            acc[1][ct] = __builtin_amdgcn_mfma_f32_16x16x32_bf16(afrag[1], bfrag, acc[1][ct], 0, 0, 0);
        }
    }

    float bv[8];
    #pragma unroll
    for (int ct = 0; ct < 8; ++ct) bv[ct] = bias[ct * 16 + llo];

    #pragma unroll
    for (int rt = 0; rt < 2; ++rt) {
        int rb = rbase + rt * 16 + lhi * 4;
        #pragma unroll
        for (int reg = 0; reg < 4; ++reg) {
            int r = rb + reg;
            if (r >= nrows) continue;
            if (OLAY == 1) {
                float* orow = (float*)outp + (size_t)r * 128;
                #pragma unroll
                for (int ct = 0; ct < 8; ++ct) {
                    float v = acc[rt][ct][reg] + bv[ct];
                    if (SILU) v = silu_f(v);
                    orow[ct * 16 + llo] = v;
                }
            } else {
                unsigned short* orow = (unsigned short*)outp + (size_t)r * 128;
                #pragma unroll
                for (int ct = 0; ct < 8; ++ct) {
                    float v = acc[rt][ct][reg] + bv[ct];
                    if (SILU) v = silu_f(v);
                    orow[ct * 16 + llo] = bf16_of(v);
                }
            }
        }
    }
}

// ---------------- Horner diffusion step, row-major bf16, deg-sorted ---------

#define ACC8(v)                                          \
    do {                                                 \
        a0 += __uint_as_float((v).x << 16);              \
        a1 += __uint_as_float((v).x & 0xffff0000u);      \
        a2 += __uint_as_float((v).y << 16);              \
        a3 += __uint_as_float((v).y & 0xffff0000u);      \
        a4 += __uint_as_float((v).z << 16);              \
        a5 += __uint_as_float((v).z & 0xffff0000u);      \
        a6 += __uint_as_float((v).w << 16);              \
        a7 += __uint_as_float((v).w & 0xffff0000u);      \
    } while (0)

__global__ __launch_bounds__(256) void horner_bf_kernel(
        const uint4v* __restrict__ u, const uint4v* __restrict__ xb,
        uint4v* __restrict__ u_next,
        const int* __restrict__ row_ptr, const int* __restrict__ ssrc,
        const int* __restrict__ perm,
        float inv_i, int nrows) {
    const int lt = threadIdx.x & 15;                 // lane within row group
    const int gid = blockIdx.x * 16 + (threadIdx.x >> 4);
    if (gid >= nrows) return;
    const int row = perm[gid];

    const int beg = row_ptr[row];
    const int end = row_ptr[row + 1];
    const int deg = end - beg;

    float a0 = 0.f, a1 = 0.f, a2 = 0.f, a3 = 0.f,
          a4 = 0.f, a5 = 0.f, a6 = 0.f, a7 = 0.f;

    int j = beg;
    for (; j + 7 < end; j += 8) {
        int s0 = ssrc[j + 0], s1 = ssrc[j + 1], s2 = ssrc[j + 2], s3 = ssrc[j + 3];
        int s4 = ssrc[j + 4], s5 = ssrc[j + 5], s6 = ssrc[j + 6], s7 = ssrc[j + 7];
        uint4v t0 = u[(size_t)s0 * 16 + lt];
        uint4v t1 = u[(size_t)s1 * 16 + lt];
        uint4v t2 = u[(size_t)s2 * 16 + lt];
        uint4v t3 = u[(size_t)s3 * 16 + lt];
        uint4v t4 = u[(size_t)s4 * 16 + lt];
        uint4v t5 = u[(size_t)s5 * 16 + lt];
        uint4v t6 = u[(size_t)s6 * 16 + lt];
        uint4v t7 = u[(size_t)s7 * 16 + lt];
        ACC8(t0); ACC8(t1); ACC8(t2); ACC8(t3);
        ACC8(t4); ACC8(t5); ACC8(t6); ACC8(t7);
    }
    for (; j + 3 < end; j += 4) {
        int s0 = ssrc[j + 0], s1 = ssrc[j + 1], s2 = ssrc[j + 2], s3 = ssrc[j + 3];
        uint4v t0 = u[(size_t)s0 * 16 + lt];
        uint4v t1 = u[(size_t)s1 * 16 + lt];
        uint4v t2 = u[(size_t)s2 * 16 + lt];
        uint4v t3 = u[(size_t)s3 * 16 + lt];
        ACC8(t0); ACC8(t1); ACC8(t2); ACC8(t3);
    }
    for (; j < end; ++j) {
        uint4v t0 = u[(size_t)ssrc[j] * 16 + lt];
        ACC8(t0);
    }

    const float scale = inv_i / (float)(deg > 1 ? deg : 1);
    const size_t o = (size_t)row * 16 + lt;
    uint4v xv = xb[o];
    float r0 = fmaf(a0, scale, __uint_as_float(xv.x << 16));
    float r1 = fmaf(a1, scale, __uint_as_float(xv.x & 0xffff0000u));
    float r2 = fmaf(a2, scale, __uint_as_float(xv.y << 16));
    float r3 = fmaf(a3, scale, __uint_as_float(xv.y & 0xffff0000u));
    float r4 = fmaf(a4, scale, __uint_as_float(xv.z << 16));
    float r5 = fmaf(a5, scale, __uint_as_float(xv.z & 0xffff0000u));
    float r6 = fmaf(a6, scale, __uint_as_float(xv.w << 16));
    float r7 = fmaf(a7, scale, __uint_as_float(xv.w & 0xffff0000u));
    uint4v ov;
    ov.x = pack_bf2(r0, r1);
    ov.y = pack_bf2(r2, r3);
    ov.z = pack_bf2(r4, r5);
    ov.w = pack_bf2(r6, r7);
    __builtin_nontemporal_store(ov, u_next + o);
}

// ---------------- launch ----------------

extern "C" void kernel_launch(void* const* d_in, const int* in_sizes, int n_in,
                              void* d_out, int out_size, void* d_ws, size_t ws_size,
                              hipStream_t stream) {
    const float* h      = (const float*)d_in[0];
    const int*   eidx   = (const int*)d_in[1];
    const float* W_in   = (const float*)d_in[2];
    const float* b_in   = (const float*)d_in[3];
    const float* W1     = (const float*)d_in[4];
    const float* b1     = (const float*)d_in[5];
    const float* W2     = (const float*)d_in[6];
    const float* b2     = (const float*)d_in[7];
    float* out = (float*)d_out;

    const int N = in_sizes[0] / D;      // 100000
    const int E = in_sizes[1] / 2;      // 1600000
    const int NB = (N + (1 << NB_SHIFT) - 1) >> NB_SHIFT;   // 196 buckets
    const int nrb = (N + 511) / 512;                        // 196 row blocks

    const int* e_src = eidx;
    const int* e_dst = eidx + E;

    // workspace layout
    unsigned short* Xb = (unsigned short*)d_ws;         // N*128 shorts (row-major bf16)
    unsigned short* U0 = Xb + (size_t)N * 128;          // N*128 shorts
    unsigned short* U1 = U0 + (size_t)N * 128;          // N*128 shorts
    unsigned short* Wt = U1 + (size_t)N * 128;          // 3*16384 shorts (bf16 W^T x3)
    unsigned* binned   = (unsigned*)(Wt + 3 * 16384);   // E
    int* ssrc        = (int*)(binned + E);              // E
    int* row_ptr     = ssrc + E;                        // N+1
    int* bucket_cnt  = row_ptr + N + 1;                 // 256
    int* bucket_base = bucket_cnt + 256;                // 256
    int* bin_cur     = bucket_base + 256;               // 256
    int* scan_part   = bin_cur + 256;                   // 256
    int* perm        = scan_part + 256;                 // N
    int* cnt         = perm + N;                        // 512*nrb (~100k)

    hipMemsetAsync(bucket_cnt, 0, 256 * sizeof(int), stream);

    const int eb = (E + 256 * CPT - 1) / (256 * CPT);
    bucket_hist_kernel<<<eb, 256, 0, stream>>>(e_dst, bucket_cnt, E, NB);
    scan_buckets_kernel<<<1, 256, 0, stream>>>(bucket_cnt, bucket_base, bin_cur, NB);
    bin_edges_kernel<<<eb, 256, 0, stream>>>(e_src, e_dst, bin_cur, binned, E, NB);
    bucket_csr_kernel<<<NB, 512, 0, stream>>>(binned, bucket_base, row_ptr, ssrc, N, E, NB);

    // degree-sorted permutation (contention-free counting sort)
    const int n_cnt = 512 * nrb;
    const int csb = (n_cnt + 511) / 512;                // = nrb (512*nrb % 512 == 0)
    deg_cnt_kernel<<<nrb, 512, 0, stream>>>(row_ptr, cnt, N, nrb);
    scan_pass1_kernel<<<csb, 512, 0, stream>>>(cnt, cnt, scan_part, n_cnt);
    scan_pass2_kernel<<<1, 256, 0, stream>>>(scan_part, csb);
    scan_pass3_kernel<<<csb, 512, 0, stream>>>(cnt, scan_part, n_cnt);
    deg_scatter_kernel<<<nrb, 512, 0, stream>>>(row_ptr, cnt, perm, N, nrb);

    // weight pre-transpose (bf16 W^T for all three GEMMs)
    transpose_w_kernel<<<192, 256, 0, stream>>>(W_in, W1, W2, Wt);

    const int gb = (N + 127) / 128;
    // Xb = bf16(silu(h @ W_in + b_in))
    gemm_mfma_kernel<0, true, 0><<<gb, 256, 0, stream>>>(h, Wt, b_in, Xb, N);

    // Horner: u = x; for i = K..1: u = x + (A u)/i   (bf16 state)
    const int db = (N + 15) / 16;
    const uint4v* Xv = (const uint4v*)Xb;
    uint4v* U0v = (uint4v*)U0;
    uint4v* U1v = (uint4v*)U1;
    horner_bf_kernel<<<db, 256, 0, stream>>>(Xv, Xv, U0v, row_ptr, ssrc, perm, 1.0f / 6.0f, N);
    horner_bf_kernel<<<db, 256, 0, stream>>>(U0v, Xv, U1v, row_ptr, ssrc, perm, 1.0f / 5.0f, N);
    horner_bf_kernel<<<db, 256, 0, stream>>>(U1v, Xv, U0v, row_ptr, ssrc, perm, 1.0f / 4.0f, N);
    horner_bf_kernel<<<db, 256, 0, stream>>>(U0v, Xv, U1v, row_ptr, ssrc, perm, 1.0f / 3.0f, N);
    horner_bf_kernel<<<db, 256, 0, stream>>>(U1v, Xv, U0v, row_ptr, ssrc, perm, 1.0f / 2.0f, N);
    horner_bf_kernel<<<db, 256, 0, stream>>>(U0v, Xv, U1v, row_ptr, ssrc, perm, 1.0f, N);
    // final diffusion result: U1 (bf16)

    // U0 = bf16(silu(U1 @ W1 + b1))
    gemm_mfma_kernel<1, true, 0><<<gb, 256, 0, stream>>>(U1, Wt + 16384, b1, U0, N);
    // out = U0 @ W2 + b2  (fp32)
    gemm_mfma_kernel<1, false, 1><<<gb, 256, 0, stream>>>(U0, Wt + 2 * 16384, b2, out, N);
}

// Round 10
// 532.192 us; speedup vs baseline: 1.5682x; 1.0557x over previous
//
#include <hip/hip_runtime.h>

#define D 128
#define K_ORDER 6
#define NB_SHIFT 9           // bucket = dst >> 9 (512 nodes/bucket)
#define CPT 8                // edges per thread in binning passes
#define BPAD 4096            // per-bucket padded slack (>= 512*7 + 8)

typedef __attribute__((ext_vector_type(8))) short short8;
typedef __attribute__((ext_vector_type(4))) float f32x4;
typedef __attribute__((ext_vector_type(4))) unsigned uint4v;

__device__ __forceinline__ float silu_f(float x) {
    return x / (1.0f + __expf(-x));
}

__device__ __forceinline__ unsigned pack_bf2(float lo, float hi) {
    unsigned ul = __float_as_uint(lo);
    unsigned uh = __float_as_uint(hi);
    ul = (ul + 0x7fffu + ((ul >> 16) & 1u)) >> 16;          // RNE
    uh = (uh + 0x7fffu + ((uh >> 16) & 1u)) & 0xffff0000u;  // RNE, keep high
    return uh | ul;
}

__device__ __forceinline__ unsigned short bf16_of(float f) {
    unsigned u = __float_as_uint(f);
    u = (u + 0x7fffu + ((u >> 16) & 1u)) >> 16;
    return (unsigned short)u;
}

// ---------------- CSR build (no global atomics on per-node arrays) ----------

__global__ __launch_bounds__(256) void bucket_hist_kernel(
        const int* __restrict__ dst, int* __restrict__ bucket_cnt, int e, int nb) {
    __shared__ int hist[256];
    for (int i = threadIdx.x; i < 256; i += 256) hist[i] = 0;
    __syncthreads();
    int i0 = blockIdx.x * (256 * CPT) + threadIdx.x;
    #pragma unroll
    for (int k = 0; k < CPT; ++k) {
        int idx = i0 + k * 256;
        if (idx < e) atomicAdd(&hist[dst[idx] >> NB_SHIFT], 1);
    }
    __syncthreads();
    for (int i = threadIdx.x; i < nb; i += 256) {
        int h = hist[i];
        if (h) atomicAdd(&bucket_cnt[i], h);
    }
}

__global__ __launch_bounds__(256) void scan_buckets_kernel(
        const int* __restrict__ bucket_cnt, int* __restrict__ bucket_base,
        int* __restrict__ bin_cur, int nb) {
    __shared__ int lds[256];
    int v = (threadIdx.x < (unsigned)nb) ? bucket_cnt[threadIdx.x] : 0;
    lds[threadIdx.x] = v;
    __syncthreads();
    #pragma unroll
    for (int off = 1; off < 256; off <<= 1) {
        int t = (threadIdx.x >= (unsigned)off) ? lds[threadIdx.x - off] : 0;
        __syncthreads();
        lds[threadIdx.x] += t;
        __syncthreads();
    }
    if (threadIdx.x < (unsigned)nb) {
        int b = lds[threadIdx.x] - v;
        bucket_base[threadIdx.x] = b;
        bin_cur[threadIdx.x] = b;
    }
}

__global__ __launch_bounds__(256) void bin_edges_kernel(
        const int* __restrict__ src, const int* __restrict__ dst,
        int* __restrict__ bin_cur, unsigned* __restrict__ binned, int e, int nb) {
    __shared__ int hist[256];
    __shared__ int base[256];
    for (int i = threadIdx.x; i < 256; i += 256) hist[i] = 0;
    __syncthreads();

    int e0 = blockIdx.x * (256 * CPT) + threadIdx.x;
    int myb[CPT], myoff[CPT];
    unsigned mypk[CPT];
    #pragma unroll
    for (int k = 0; k < CPT; ++k) {
        int idx = e0 + k * 256;
        bool ok = idx < e;
        int d = ok ? dst[idx] : 0;
        int s = ok ? src[idx] : 0;
        int b = d >> NB_SHIFT;
        int off = ok ? atomicAdd(&hist[b], 1) : 0;
        myb[k] = b; myoff[k] = off;
        mypk[k] = ((unsigned)s << NB_SHIFT) | (unsigned)(d & ((1 << NB_SHIFT) - 1));
    }
    __syncthreads();
    for (int i = threadIdx.x; i < nb; i += 256) {
        int h = hist[i];
        base[i] = h ? atomicAdd(&bin_cur[i], h) : 0;
    }
    __syncthreads();
    #pragma unroll
    for (int k = 0; k < CPT; ++k) {
        int idx = e0 + k * 256;
        if (idx < e)
            binned[(size_t)base[myb[k]] + myoff[k]] = mypk[k];
    }
}

// Per-bucket CSR finalize with 8-padding: each row's edge list is padded to a
// multiple of 8 with dummy src = n (zero feature row). row_start is 8-aligned.
__global__ __launch_bounds__(512) void bucket_csr_kernel(
        const unsigned* __restrict__ binned, const int* __restrict__ bucket_base,
        int* __restrict__ row_start, int* __restrict__ degv,
        int* __restrict__ ssrc, int n, int e, int nb) {
    __shared__ int hist[512];
    __shared__ int pfx[512];
    const int b = blockIdx.x;
    const int node0 = b << NB_SHIFT;
    const int beg = bucket_base[b];
    const int end = (b + 1 < nb) ? bucket_base[b + 1] : e;
    const int pbeg = ((beg + 7) & ~7) + b * BPAD;    // padded bucket base (8-aligned)

    hist[threadIdx.x] = 0;
    __syncthreads();
    for (int j = beg + (int)threadIdx.x; j < end; j += 512)
        atomicAdd(&hist[binned[j] & 511u], 1);
    __syncthreads();

    const int mydeg = hist[threadIdx.x];
    const int mypc = (mydeg + 7) & ~7;               // padded count
    pfx[threadIdx.x] = mypc;
    __syncthreads();
    #pragma unroll
    for (int off = 1; off < 512; off <<= 1) {
        int t = (threadIdx.x >= (unsigned)off) ? pfx[threadIdx.x - off] : 0;
        __syncthreads();
        pfx[threadIdx.x] += t;
        __syncthreads();
    }
    const int myexcl = pfx[threadIdx.x] - mypc;

    const int node = node0 + (int)threadIdx.x;
    if (node < n) {
        row_start[node] = pbeg + myexcl;
        degv[node] = mydeg;
    }
    __syncthreads();

    pfx[threadIdx.x] = myexcl;   // per-node padded start (exclusive)
    hist[threadIdx.x] = 0;       // reuse as per-node cursor
    __syncthreads();

    for (int j = beg + (int)threadIdx.x; j < end; j += 512) {
        unsigned p = binned[j];
        int dl = (int)(p & 511u);
        int pos = pbeg + pfx[dl] + atomicAdd(&hist[dl], 1);
        ssrc[pos] = (int)(p >> NB_SHIFT);
    }
    __syncthreads();

    // fill pad slots of own node with dummy src = n (zero row)
    if (node < n) {
        int base = pbeg + myexcl;
        for (int k = mydeg; k < mypc; ++k) ssrc[base + k] = n;
    }
}

// ---------------- weight pre-transpose: W (f32 row-major) -> W^T bf16 -------
__global__ __launch_bounds__(256) void transpose_w_kernel(
        const float* __restrict__ W0, const float* __restrict__ W1,
        const float* __restrict__ W2, unsigned short* __restrict__ Wt) {
    int i = blockIdx.x * 256 + threadIdx.x;     // 0 .. 3*16384-1
    int w = i >> 14;
    int r = i & 16383;
    int k = r >> 7, c = r & 127;
    const float* W = (w == 0) ? W0 : ((w == 1) ? W1 : W2);
    Wt[(size_t)w * 16384 + c * 128 + k] = bf16_of(W[r]);
}

// ---------------- MFMA GEMM: [nrows x 128] @ [128 x 128], no LDS -----------
// ALAY: 0 = fp32 A, 1 = bf16 A.  OLAY: 0 = bf16 out, 1 = fp32 out.
template <int ALAY, bool SILU, int OLAY>
__global__ __launch_bounds__(256) void gemm_mfma_kernel(
        const void* __restrict__ Ap, const unsigned short* __restrict__ Wt,
        const float* __restrict__ bias, void* __restrict__ outp, int nrows) {
    const int wave = threadIdx.x >> 6;
    const int lane = threadIdx.x & 63;
    const int lhi = lane >> 4;
    const int llo = lane & 15;

    const int rbase = blockIdx.x * 128 + wave * 32;

    f32x4 acc[2][8] = {};

    #pragma unroll
    for (int ks = 0; ks < 4; ++ks) {
        const int k0 = ks * 32 + lhi * 8;
        short8 afrag[2];
        #pragma unroll
        for (int rt = 0; rt < 2; ++rt) {
            int r = rbase + rt * 16 + llo;
            if (r < nrows) {
                if (ALAY == 0) {
                    const float* ap = (const float*)Ap + (size_t)r * 128 + k0;
                    float4 f0 = *(const float4*)ap;
                    float4 f1 = *(const float4*)(ap + 4);
                    union { unsigned u[4]; short8 s; } cvt;
                    cvt.u[0] = pack_bf2(f0.x, f0.y);
                    cvt.u[1] = pack_bf2(f0.z, f0.w);
                    cvt.u[2] = pack_bf2(f1.x, f1.y);
                    cvt.u[3] = pack_bf2(f1.z, f1.w);
                    afrag[rt] = cvt.s;
                } else {
                    afrag[rt] = *(const short8*)((const unsigned short*)Ap + (size_t)r * 128 + k0);
                }
            } else {
                afrag[rt] = short8{0, 0, 0, 0, 0, 0, 0, 0};
            }
        }
        #pragma unroll
        for (int ct = 0; ct < 8; ++ct) {
            short8 bfrag = *(const short8*)(Wt + (size_t)(ct * 16 + llo) * 128 + k0);
            acc[0][ct] = __builtin_amdgcn_mfma_f32_16x16x32_bf16(afrag[0], bfrag, acc[0][ct], 0, 0, 0);
            acc[1][ct] = __builtin_amdgcn_mfma_f32_16x16x32_bf16(afrag[1], bfrag, acc[1][ct], 0, 0, 0);
        }
    }

    float bv[8];
    #pragma unroll
    for (int ct = 0; ct < 8; ++ct) bv[ct] = bias[ct * 16 + llo];

    #pragma unroll
    for (int rt = 0; rt < 2; ++rt) {
        int rb = rbase + rt * 16 + lhi * 4;
        #pragma unroll
        for (int reg = 0; reg < 4; ++reg) {
            int r = rb + reg;
            if (r >= nrows) continue;
            if (OLAY == 1) {
                float* orow = (float*)outp + (size_t)r * 128;
                #pragma unroll
                for (int ct = 0; ct < 8; ++ct) {
                    float v = acc[rt][ct][reg] + bv[ct];
                    if (SILU) v = silu_f(v);
                    orow[ct * 16 + llo] = v;
                }
            } else {
                unsigned short* orow = (unsigned short*)outp + (size_t)r * 128;
                #pragma unroll
                for (int ct = 0; ct < 8; ++ct) {
                    float v = acc[rt][ct][reg] + bv[ct];
                    if (SILU) v = silu_f(v);
                    orow[ct * 16 + llo] = bf16_of(v);
                }
            }
        }
    }
}

// ---------------- Horner diffusion step, row-major bf16, padded CSR ---------
// u_next = x + (inv_i / deg) * (A u). 16 lanes per row, uint4 (16 B = 8 feats)
// per lane. Edge lists padded to x8 (dummy -> zero row): no tails, int4 index
// loads. Plain (cached) loads/stores: u_next seeds next step's gathers, x is
// re-read every step.

#define ACC8(v)                                          \
    do {                                                 \
        a0 += __uint_as_float((v).x << 16);              \
        a1 += __uint_as_float((v).x & 0xffff0000u);      \
        a2 += __uint_as_float((v).y << 16);              \
        a3 += __uint_as_float((v).y & 0xffff0000u);      \
        a4 += __uint_as_float((v).z << 16);              \
        a5 += __uint_as_float((v).z & 0xffff0000u);      \
        a6 += __uint_as_float((v).w << 16);              \
        a7 += __uint_as_float((v).w & 0xffff0000u);      \
    } while (0)

__global__ __launch_bounds__(256) void horner_bf_kernel(
        const uint4v* __restrict__ u, const uint4v* __restrict__ xb,
        uint4v* __restrict__ u_next,
        const int* __restrict__ row_start, const int* __restrict__ degv,
        const int* __restrict__ ssrc,
        float inv_i, int nrows) {
    const int lt = threadIdx.x & 15;                 // lane within row group
    const int row = blockIdx.x * 16 + (threadIdx.x >> 4);
    if (row >= nrows) return;

    const int beg = row_start[row];
    const int deg = degv[row];
    const int pend = beg + ((deg + 7) & ~7);

    float a0 = 0.f, a1 = 0.f, a2 = 0.f, a3 = 0.f,
          a4 = 0.f, a5 = 0.f, a6 = 0.f, a7 = 0.f;

    for (int j = beg; j < pend; j += 8) {
        int4 sA = *(const int4*)(ssrc + j);
        int4 sB = *(const int4*)(ssrc + j + 4);
        uint4v t0 = u[(size_t)sA.x * 16 + lt];
        uint4v t1 = u[(size_t)sA.y * 16 + lt];
        uint4v t2 = u[(size_t)sA.z * 16 + lt];
        uint4v t3 = u[(size_t)sA.w * 16 + lt];
        uint4v t4 = u[(size_t)sB.x * 16 + lt];
        uint4v t5 = u[(size_t)sB.y * 16 + lt];
        uint4v t6 = u[(size_t)sB.z * 16 + lt];
        uint4v t7 = u[(size_t)sB.w * 16 + lt];
        ACC8(t0); ACC8(t1); ACC8(t2); ACC8(t3);
        ACC8(t4); ACC8(t5); ACC8(t6); ACC8(t7);
    }

    const float scale = inv_i / (float)(deg > 1 ? deg : 1);
    const size_t o = (size_t)row * 16 + lt;
    uint4v xv = xb[o];
    float r0 = fmaf(a0, scale, __uint_as_float(xv.x << 16));
    float r1 = fmaf(a1, scale, __uint_as_float(xv.x & 0xffff0000u));
    float r2 = fmaf(a2, scale, __uint_as_float(xv.y << 16));
    float r3 = fmaf(a3, scale, __uint_as_float(xv.y & 0xffff0000u));
    float r4 = fmaf(a4, scale, __uint_as_float(xv.z << 16));
    float r5 = fmaf(a5, scale, __uint_as_float(xv.z & 0xffff0000u));
    float r6 = fmaf(a6, scale, __uint_as_float(xv.w << 16));
    float r7 = fmaf(a7, scale, __uint_as_float(xv.w & 0xffff0000u));
    uint4v ov;
    ov.x = pack_bf2(r0, r1);
    ov.y = pack_bf2(r2, r3);
    ov.z = pack_bf2(r4, r5);
    ov.w = pack_bf2(r6, r7);
    u_next[o] = ov;
}

// ---------------- launch ----------------

extern "C" void kernel_launch(void* const* d_in, const int* in_sizes, int n_in,
                              void* d_out, int out_size, void* d_ws, size_t ws_size,
                              hipStream_t stream) {
    const float* h      = (const float*)d_in[0];
    const int*   eidx   = (const int*)d_in[1];
    const float* W_in   = (const float*)d_in[2];
    const float* b_in   = (const float*)d_in[3];
    const float* W1     = (const float*)d_in[4];
    const float* b1     = (const float*)d_in[5];
    const float* W2     = (const float*)d_in[6];
    const float* b2     = (const float*)d_in[7];
    float* out = (float*)d_out;

    const int N = in_sizes[0] / D;      // 100000
    const int E = in_sizes[1] / 2;      // 1600000
    const int NB = (N + (1 << NB_SHIFT) - 1) >> NB_SHIFT;   // 196 buckets

    const int* e_src = eidx;
    const int* e_dst = eidx + E;

    const size_t rowsz = (size_t)(N + 1) * 128;   // +1 zero row for dummy edges

    // workspace layout
    unsigned short* Xb = (unsigned short*)d_ws;         // (N+1)*128 shorts
    unsigned short* U0 = Xb + rowsz;                    // (N+1)*128 shorts
    unsigned short* U1 = U0 + rowsz;                    // (N+1)*128 shorts
    unsigned short* Wt = U1 + rowsz;                    // 3*16384 shorts
    unsigned* binned   = (unsigned*)(Wt + 3 * 16384);   // E
    int* ssrc        = (int*)(binned + E);              // E + NB*BPAD + 16
    int* row_start   = ssrc + E + NB * BPAD + 16;       // N
    int* degv        = row_start + N;                   // N
    int* bucket_cnt  = degv + N;                        // 256
    int* bucket_base = bucket_cnt + 256;                // 256
    int* bin_cur     = bucket_base + 256;               // 256

    hipMemsetAsync(bucket_cnt, 0, 256 * sizeof(int), stream);
    // zero feature row N in all three state buffers (dummy-edge target)
    hipMemsetAsync(Xb + (size_t)N * 128, 0, 256, stream);
    hipMemsetAsync(U0 + (size_t)N * 128, 0, 256, stream);
    hipMemsetAsync(U1 + (size_t)N * 128, 0, 256, stream);

    const int eb = (E + 256 * CPT - 1) / (256 * CPT);
    bucket_hist_kernel<<<eb, 256, 0, stream>>>(e_dst, bucket_cnt, E, NB);
    scan_buckets_kernel<<<1, 256, 0, stream>>>(bucket_cnt, bucket_base, bin_cur, NB);
    bin_edges_kernel<<<eb, 256, 0, stream>>>(e_src, e_dst, bin_cur, binned, E, NB);
    bucket_csr_kernel<<<NB, 512, 0, stream>>>(binned, bucket_base, row_start, degv,
                                              ssrc, N, E, NB);

    // weight pre-transpose (bf16 W^T for all three GEMMs)
    transpose_w_kernel<<<192, 256, 0, stream>>>(W_in, W1, W2, Wt);

    const int gb = (N + 127) / 128;
    // Xb = bf16(silu(h @ W_in + b_in))
    gemm_mfma_kernel<0, true, 0><<<gb, 256, 0, stream>>>(h, Wt, b_in, Xb, N);

    // Horner: u = x; for i = K..1: u = x + (A u)/i   (bf16 state)
    const int db = (N + 15) / 16;
    const uint4v* Xv = (const uint4v*)Xb;
    uint4v* U0v = (uint4v*)U0;
    uint4v* U1v = (uint4v*)U1;
    horner_bf_kernel<<<db, 256, 0, stream>>>(Xv, Xv, U0v, row_start, degv, ssrc, 1.0f / 6.0f, N);
    horner_bf_kernel<<<db, 256, 0, stream>>>(U0v, Xv, U1v, row_start, degv, ssrc, 1.0f / 5.0f, N);
    horner_bf_kernel<<<db, 256, 0, stream>>>(U1v, Xv, U0v, row_start, degv, ssrc, 1.0f / 4.0f, N);
    horner_bf_kernel<<<db, 256, 0, stream>>>(U0v, Xv, U1v, row_start, degv, ssrc, 1.0f / 3.0f, N);
    horner_bf_kernel<<<db, 256, 0, stream>>>(U1v, Xv, U0v, row_start, degv, ssrc, 1.0f / 2.0f, N);
    horner_bf_kernel<<<db, 256, 0, stream>>>(U0v, Xv, U1v, row_start, degv, ssrc, 1.0f, N);
    // final diffusion result: U1 (bf16)

    // U0 = bf16(silu(U1 @ W1 + b1))
    gemm_mfma_kernel<1, true, 0><<<gb, 256, 0, stream>>>(U1, Wt + 16384, b1, U0, N);
    // out = U0 @ W2 + b2  (fp32)
    gemm_mfma_kernel<1, false, 1><<<gb, 256, 0, stream>>>(U0, Wt + 2 * 16384, b2, out, N);
}

// Round 11
// 520.482 us; speedup vs baseline: 1.6034x; 1.0225x over previous
//
#include <hip/hip_runtime.h>

#define D 128
#define K_ORDER 6
#define NB_SHIFT 9           // bucket = dst >> 9 (512 nodes/bucket)
#define CPT 8                // edges per thread in binning passes
#define BPAD 4096            // per-bucket padded slack (>= 512*7 + 8)

typedef __attribute__((ext_vector_type(8))) short short8;
typedef __attribute__((ext_vector_type(4))) float f32x4;
typedef __attribute__((ext_vector_type(4))) unsigned uint4v;

__device__ __forceinline__ float silu_f(float x) {
    return x / (1.0f + __expf(-x));
}

__device__ __forceinline__ unsigned pack_bf2(float lo, float hi) {
    unsigned ul = __float_as_uint(lo);
    unsigned uh = __float_as_uint(hi);
    ul = (ul + 0x7fffu + ((ul >> 16) & 1u)) >> 16;          // RNE
    uh = (uh + 0x7fffu + ((uh >> 16) & 1u)) & 0xffff0000u;  // RNE, keep high
    return uh | ul;
}

__device__ __forceinline__ unsigned short bf16_of(float f) {
    unsigned u = __float_as_uint(f);
    u = (u + 0x7fffu + ((u >> 16) & 1u)) >> 16;
    return (unsigned short)u;
}

// ---------------- CSR build (no global atomics on per-node arrays) ----------

__global__ __launch_bounds__(256) void bucket_hist_kernel(
        const int* __restrict__ dst, int* __restrict__ bucket_cnt, int e, int nb) {
    __shared__ int hist[256];
    for (int i = threadIdx.x; i < 256; i += 256) hist[i] = 0;
    __syncthreads();
    int i0 = blockIdx.x * (256 * CPT) + threadIdx.x;
    #pragma unroll
    for (int k = 0; k < CPT; ++k) {
        int idx = i0 + k * 256;
        if (idx < e) atomicAdd(&hist[dst[idx] >> NB_SHIFT], 1);
    }
    __syncthreads();
    for (int i = threadIdx.x; i < nb; i += 256) {
        int h = hist[i];
        if (h) atomicAdd(&bucket_cnt[i], h);
    }
}

__global__ __launch_bounds__(256) void scan_buckets_kernel(
        const int* __restrict__ bucket_cnt, int* __restrict__ bucket_base,
        int* __restrict__ bin_cur, int nb) {
    __shared__ int lds[256];
    int v = (threadIdx.x < (unsigned)nb) ? bucket_cnt[threadIdx.x] : 0;
    lds[threadIdx.x] = v;
    __syncthreads();
    #pragma unroll
    for (int off = 1; off < 256; off <<= 1) {
        int t = (threadIdx.x >= (unsigned)off) ? lds[threadIdx.x - off] : 0;
        __syncthreads();
        lds[threadIdx.x] += t;
        __syncthreads();
    }
    if (threadIdx.x < (unsigned)nb) {
        int b = lds[threadIdx.x] - v;
        bucket_base[threadIdx.x] = b;
        bin_cur[threadIdx.x] = b;
    }
}

__global__ __launch_bounds__(256) void bin_edges_kernel(
        const int* __restrict__ src, const int* __restrict__ dst,
        int* __restrict__ bin_cur, unsigned* __restrict__ binned, int e, int nb) {
    __shared__ int hist[256];
    __shared__ int base[256];
    for (int i = threadIdx.x; i < 256; i += 256) hist[i] = 0;
    __syncthreads();

    int e0 = blockIdx.x * (256 * CPT) + threadIdx.x;
    int myb[CPT], myoff[CPT];
    unsigned mypk[CPT];
    #pragma unroll
    for (int k = 0; k < CPT; ++k) {
        int idx = e0 + k * 256;
        bool ok = idx < e;
        int d = ok ? dst[idx] : 0;
        int s = ok ? src[idx] : 0;
        int b = d >> NB_SHIFT;
        int off = ok ? atomicAdd(&hist[b], 1) : 0;
        myb[k] = b; myoff[k] = off;
        mypk[k] = ((unsigned)s << NB_SHIFT) | (unsigned)(d & ((1 << NB_SHIFT) - 1));
    }
    __syncthreads();
    for (int i = threadIdx.x; i < nb; i += 256) {
        int h = hist[i];
        base[i] = h ? atomicAdd(&bin_cur[i], h) : 0;
    }
    __syncthreads();
    #pragma unroll
    for (int k = 0; k < CPT; ++k) {
        int idx = e0 + k * 256;
        if (idx < e)
            binned[(size_t)base[myb[k]] + myoff[k]] = mypk[k];
    }
}

// Per-bucket CSR finalize with 8-padding: each row's edge list is padded to a
// multiple of 8 with dummy src = n (zero feature row). row_start is 8-aligned.
__global__ __launch_bounds__(512) void bucket_csr_kernel(
        const unsigned* __restrict__ binned, const int* __restrict__ bucket_base,
        int* __restrict__ row_start, int* __restrict__ degv,
        int* __restrict__ ssrc, int n, int e, int nb) {
    __shared__ int hist[512];
    __shared__ int pfx[512];
    const int b = blockIdx.x;
    const int node0 = b << NB_SHIFT;
    const int beg = bucket_base[b];
    const int end = (b + 1 < nb) ? bucket_base[b + 1] : e;
    const int pbeg = ((beg + 7) & ~7) + b * BPAD;    // padded bucket base (8-aligned)

    hist[threadIdx.x] = 0;
    __syncthreads();
    for (int j = beg + (int)threadIdx.x; j < end; j += 512)
        atomicAdd(&hist[binned[j] & 511u], 1);
    __syncthreads();

    const int mydeg = hist[threadIdx.x];
    const int mypc = (mydeg + 7) & ~7;               // padded count
    pfx[threadIdx.x] = mypc;
    __syncthreads();
    #pragma unroll
    for (int off = 1; off < 512; off <<= 1) {
        int t = (threadIdx.x >= (unsigned)off) ? pfx[threadIdx.x - off] : 0;
        __syncthreads();
        pfx[threadIdx.x] += t;
        __syncthreads();
    }
    const int myexcl = pfx[threadIdx.x] - mypc;

    const int node = node0 + (int)threadIdx.x;
    if (node < n) {
        row_start[node] = pbeg + myexcl;
        degv[node] = mydeg;
    }
    __syncthreads();

    pfx[threadIdx.x] = myexcl;   // per-node padded start (exclusive)
    hist[threadIdx.x] = 0;       // reuse as per-node cursor
    __syncthreads();

    for (int j = beg + (int)threadIdx.x; j < end; j += 512) {
        unsigned p = binned[j];
        int dl = (int)(p & 511u);
        int pos = pbeg + pfx[dl] + atomicAdd(&hist[dl], 1);
        ssrc[pos] = (int)(p >> NB_SHIFT);
    }
    __syncthreads();

    // fill pad slots of own node with dummy src = n (zero row)
    if (node < n) {
        int base = pbeg + myexcl;
        for (int k = mydeg; k < mypc; ++k) ssrc[base + k] = n;
    }
}

// ---------------- weight pre-transpose: W (f32 row-major) -> W^T bf16 -------
__global__ __launch_bounds__(256) void transpose_w_kernel(
        const float* __restrict__ W0, const float* __restrict__ W1,
        const float* __restrict__ W2, unsigned short* __restrict__ Wt) {
    int i = blockIdx.x * 256 + threadIdx.x;     // 0 .. 3*16384-1
    int w = i >> 14;
    int r = i & 16383;
    int k = r >> 7, c = r & 127;
    const float* W = (w == 0) ? W0 : ((w == 1) ? W1 : W2);
    Wt[(size_t)w * 16384 + c * 128 + k] = bf16_of(W[r]);
}

// ---------------- MFMA GEMM 1: [nrows x 128] fp32 @ W_in -> bf16, no LDS ----
__global__ __launch_bounds__(256) void gemm1_kernel(
        const float* __restrict__ Ap, const unsigned short* __restrict__ Wt,
        const float* __restrict__ bias, unsigned short* __restrict__ outp, int nrows) {
    const int wave = threadIdx.x >> 6;
    const int lane = threadIdx.x & 63;
    const int lhi = lane >> 4;
    const int llo = lane & 15;

    const int rbase = blockIdx.x * 128 + wave * 32;

    f32x4 acc[2][8] = {};

    #pragma unroll
    for (int ks = 0; ks < 4; ++ks) {
        const int k0 = ks * 32 + lhi * 8;
        short8 afrag[2];
        #pragma unroll
        for (int rt = 0; rt < 2; ++rt) {
            int r = rbase + rt * 16 + llo;
            if (r < nrows) {
                const float* ap = Ap + (size_t)r * 128 + k0;
                float4 f0 = *(const float4*)ap;
                float4 f1 = *(const float4*)(ap + 4);
                union { unsigned u[4]; short8 s; } cvt;
                cvt.u[0] = pack_bf2(f0.x, f0.y);
                cvt.u[1] = pack_bf2(f0.z, f0.w);
                cvt.u[2] = pack_bf2(f1.x, f1.y);
                cvt.u[3] = pack_bf2(f1.z, f1.w);
                afrag[rt] = cvt.s;
            } else {
                afrag[rt] = short8{0, 0, 0, 0, 0, 0, 0, 0};
            }
        }
        #pragma unroll
        for (int ct = 0; ct < 8; ++ct) {
            short8 bfrag = *(const short8*)(Wt + (size_t)(ct * 16 + llo) * 128 + k0);
            acc[0][ct] = __builtin_amdgcn_mfma_f32_16x16x32_bf16(afrag[0], bfrag, acc[0][ct], 0, 0, 0);
            acc[1][ct] = __builtin_amdgcn_mfma_f32_16x16x32_bf16(afrag[1], bfrag, acc[1][ct], 0, 0, 0);
        }
    }

    float bv[8];
    #pragma unroll
    for (int ct = 0; ct < 8; ++ct) bv[ct] = bias[ct * 16 + llo];

    #pragma unroll
    for (int rt = 0; rt < 2; ++rt) {
        int rb = rbase + rt * 16 + lhi * 4;
        #pragma unroll
        for (int reg = 0; reg < 4; ++reg) {
            int r = rb + reg;
            if (r >= nrows) continue;
            unsigned short* orow = outp + (size_t)r * 128;
            #pragma unroll
            for (int ct = 0; ct < 8; ++ct) {
                float v = silu_f(acc[rt][ct][reg] + bv[ct]);
                orow[ct * 16 + llo] = bf16_of(v);
            }
        }
    }
}

// ---------------- fused GEMM2+GEMM3: out = silu(U@W1+b1) @ W2 + b2 ----------
// Phase 1 -> silu bf16 tile in LDS (128 x 136 pad); phase 2 consumes it as
// A-frags (ds_read_b128, 2-way bank alias = free). x2 never touches HBM.
__global__ __launch_bounds__(256) void gemm23_fused_kernel(
        const unsigned short* __restrict__ U,
        const unsigned short* __restrict__ W1t, const float* __restrict__ b1,
        const unsigned short* __restrict__ W2t, const float* __restrict__ b2,
        float* __restrict__ out, int nrows) {
    constexpr int LDX = 136;
    __shared__ unsigned short sX[128 * LDX];   // ~34.8 KB

    const int wave = threadIdx.x >> 6;
    const int lane = threadIdx.x & 63;
    const int lhi = lane >> 4;
    const int llo = lane & 15;

    const int rbase = blockIdx.x * 128 + wave * 32;
    const int lbase = wave * 32;

    // ---- phase 1: acc = U_tile @ W1 ----
    {
        f32x4 acc[2][8] = {};
        #pragma unroll
        for (int ks = 0; ks < 4; ++ks) {
            const int k0 = ks * 32 + lhi * 8;
            short8 afrag[2];
            #pragma unroll
            for (int rt = 0; rt < 2; ++rt) {
                int r = rbase + rt * 16 + llo;
                afrag[rt] = (r < nrows)
                    ? *(const short8*)(U + (size_t)r * 128 + k0)
                    : short8{0, 0, 0, 0, 0, 0, 0, 0};
            }
            #pragma unroll
            for (int ct = 0; ct < 8; ++ct) {
                short8 bfrag = *(const short8*)(W1t + (size_t)(ct * 16 + llo) * 128 + k0);
                acc[0][ct] = __builtin_amdgcn_mfma_f32_16x16x32_bf16(afrag[0], bfrag, acc[0][ct], 0, 0, 0);
                acc[1][ct] = __builtin_amdgcn_mfma_f32_16x16x32_bf16(afrag[1], bfrag, acc[1][ct], 0, 0, 0);
            }
        }
        float bv[8];
        #pragma unroll
        for (int ct = 0; ct < 8; ++ct) bv[ct] = b1[ct * 16 + llo];
        #pragma unroll
        for (int rt = 0; rt < 2; ++rt) {
            int lr = lbase + rt * 16 + lhi * 4;
            #pragma unroll
            for (int reg = 0; reg < 4; ++reg) {
                unsigned short* srow = sX + (size_t)(lr + reg) * LDX;
                #pragma unroll
                for (int ct = 0; ct < 8; ++ct) {
                    float v = silu_f(acc[rt][ct][reg] + bv[ct]);
                    srow[ct * 16 + llo] = bf16_of(v);
                }
            }
        }
    }
    __syncthreads();

    // ---- phase 2: out = sX @ W2 + b2 ----
    f32x4 acc[2][8] = {};
    #pragma unroll
    for (int ks = 0; ks < 4; ++ks) {
        const int k0 = ks * 32 + lhi * 8;
        short8 afrag[2];
        #pragma unroll
        for (int rt = 0; rt < 2; ++rt) {
            int lr = lbase + rt * 16 + llo;
            afrag[rt] = *(const short8*)(sX + (size_t)lr * LDX + k0);
        }
        #pragma unroll
        for (int ct = 0; ct < 8; ++ct) {
            short8 bfrag = *(const short8*)(W2t + (size_t)(ct * 16 + llo) * 128 + k0);
            acc[0][ct] = __builtin_amdgcn_mfma_f32_16x16x32_bf16(afrag[0], bfrag, acc[0][ct], 0, 0, 0);
            acc[1][ct] = __builtin_amdgcn_mfma_f32_16x16x32_bf16(afrag[1], bfrag, acc[1][ct], 0, 0, 0);
        }
    }
    float bv[8];
    #pragma unroll
    for (int ct = 0; ct < 8; ++ct) bv[ct] = b2[ct * 16 + llo];
    #pragma unroll
    for (int rt = 0; rt < 2; ++rt) {
        int rb = rbase + rt * 16 + lhi * 4;
        #pragma unroll
        for (int reg = 0; reg < 4; ++reg) {
            int r = rb + reg;
            if (r >= nrows) continue;
            float* orow = out + (size_t)r * 128;
            #pragma unroll
            for (int ct = 0; ct < 8; ++ct)
                orow[ct * 16 + llo] = acc[rt][ct][reg] + bv[ct];
        }
    }
}

// ---------------- Horner diffusion step, row-major bf16, padded CSR ---------

#define ACC8(v)                                          \
    do {                                                 \
        a0 += __uint_as_float((v).x << 16);              \
        a1 += __uint_as_float((v).x & 0xffff0000u);      \
        a2 += __uint_as_float((v).y << 16);              \
        a3 += __uint_as_float((v).y & 0xffff0000u);      \
        a4 += __uint_as_float((v).z << 16);              \
        a5 += __uint_as_float((v).z & 0xffff0000u);      \
        a6 += __uint_as_float((v).w << 16);              \
        a7 += __uint_as_float((v).w & 0xffff0000u);      \
    } while (0)

__global__ __launch_bounds__(256) void horner_bf_kernel(
        const uint4v* __restrict__ u, const uint4v* __restrict__ xb,
        uint4v* __restrict__ u_next,
        const int* __restrict__ row_start, const int* __restrict__ degv,
        const int* __restrict__ ssrc,
        float inv_i, int nrows) {
    const int lt = threadIdx.x & 15;                 // lane within row group
    const int row = blockIdx.x * 16 + (threadIdx.x >> 4);
    if (row >= nrows) return;

    const int beg = row_start[row];
    const int deg = degv[row];
    const int pend = beg + ((deg + 7) & ~7);

    float a0 = 0.f, a1 = 0.f, a2 = 0.f, a3 = 0.f,
          a4 = 0.f, a5 = 0.f, a6 = 0.f, a7 = 0.f;

    for (int j = beg; j < pend; j += 8) {
        int4 sA = *(const int4*)(ssrc + j);
        int4 sB = *(const int4*)(ssrc + j + 4);
        uint4v t0 = u[(size_t)sA.x * 16 + lt];
        uint4v t1 = u[(size_t)sA.y * 16 + lt];
        uint4v t2 = u[(size_t)sA.z * 16 + lt];
        uint4v t3 = u[(size_t)sA.w * 16 + lt];
        uint4v t4 = u[(size_t)sB.x * 16 + lt];
        uint4v t5 = u[(size_t)sB.y * 16 + lt];
        uint4v t6 = u[(size_t)sB.z * 16 + lt];
        uint4v t7 = u[(size_t)sB.w * 16 + lt];
        ACC8(t0); ACC8(t1); ACC8(t2); ACC8(t3);
        ACC8(t4); ACC8(t5); ACC8(t6); ACC8(t7);
    }

    const float scale = inv_i / (float)(deg > 1 ? deg : 1);
    const size_t o = (size_t)row * 16 + lt;
    uint4v xv = xb[o];
    float r0 = fmaf(a0, scale, __uint_as_float(xv.x << 16));
    float r1 = fmaf(a1, scale, __uint_as_float(xv.x & 0xffff0000u));
    float r2 = fmaf(a2, scale, __uint_as_float(xv.y << 16));
    float r3 = fmaf(a3, scale, __uint_as_float(xv.y & 0xffff0000u));
    float r4 = fmaf(a4, scale, __uint_as_float(xv.z << 16));
    float r5 = fmaf(a5, scale, __uint_as_float(xv.z & 0xffff0000u));
    float r6 = fmaf(a6, scale, __uint_as_float(xv.w << 16));
    float r7 = fmaf(a7, scale, __uint_as_float(xv.w & 0xffff0000u));
    uint4v ov;
    ov.x = pack_bf2(r0, r1);
    ov.y = pack_bf2(r2, r3);
    ov.z = pack_bf2(r4, r5);
    ov.w = pack_bf2(r6, r7);
    u_next[o] = ov;
}

// ---------------- launch ----------------

extern "C" void kernel_launch(void* const* d_in, const int* in_sizes, int n_in,
                              void* d_out, int out_size, void* d_ws, size_t ws_size,
                              hipStream_t stream) {
    const float* h      = (const float*)d_in[0];
    const int*   eidx   = (const int*)d_in[1];
    const float* W_in   = (const float*)d_in[2];
    const float* b_in   = (const float*)d_in[3];
    const float* W1     = (const float*)d_in[4];
    const float* b1     = (const float*)d_in[5];
    const float* W2     = (const float*)d_in[6];
    const float* b2     = (const float*)d_in[7];
    float* out = (float*)d_out;

    const int N = in_sizes[0] / D;      // 100000
    const int E = in_sizes[1] / 2;      // 1600000
    const int NB = (N + (1 << NB_SHIFT) - 1) >> NB_SHIFT;   // 196 buckets

    const int* e_src = eidx;
    const int* e_dst = eidx + E;

    const size_t rowsz = (size_t)(N + 1) * 128;   // +1 zero row for dummy edges

    // workspace layout
    unsigned short* Xb = (unsigned short*)d_ws;         // (N+1)*128 shorts
    unsigned short* U0 = Xb + rowsz;                    // (N+1)*128 shorts
    unsigned short* U1 = U0 + rowsz;                    // (N+1)*128 shorts
    unsigned short* Wt = U1 + rowsz;                    // 3*16384 shorts
    unsigned* binned   = (unsigned*)(Wt + 3 * 16384);   // E
    int* ssrc        = (int*)(binned + E);              // E + NB*BPAD + 16
    int* row_start   = ssrc + E + NB * BPAD + 16;       // N
    int* degv        = row_start + N;                   // N
    int* bucket_cnt  = degv + N;                        // 256
    int* bucket_base = bucket_cnt + 256;                // 256
    int* bin_cur     = bucket_base + 256;               // 256

    hipMemsetAsync(bucket_cnt, 0, 256 * sizeof(int), stream);
    // zero feature row N in all three state buffers (dummy-edge target)
    hipMemsetAsync(Xb + (size_t)N * 128, 0, 256, stream);
    hipMemsetAsync(U0 + (size_t)N * 128, 0, 256, stream);
    hipMemsetAsync(U1 + (size_t)N * 128, 0, 256, stream);

    const int eb = (E + 256 * CPT - 1) / (256 * CPT);
    bucket_hist_kernel<<<eb, 256, 0, stream>>>(e_dst, bucket_cnt, E, NB);
    scan_buckets_kernel<<<1, 256, 0, stream>>>(bucket_cnt, bucket_base, bin_cur, NB);
    bin_edges_kernel<<<eb, 256, 0, stream>>>(e_src, e_dst, bin_cur, binned, E, NB);
    bucket_csr_kernel<<<NB, 512, 0, stream>>>(binned, bucket_base, row_start, degv,
                                              ssrc, N, E, NB);

    // weight pre-transpose (bf16 W^T for all three GEMMs)
    transpose_w_kernel<<<192, 256, 0, stream>>>(W_in, W1, W2, Wt);

    const int gb = (N + 127) / 128;
    // Xb = bf16(silu(h @ W_in + b_in))
    gemm1_kernel<<<gb, 256, 0, stream>>>(h, Wt, b_in, Xb, N);

    // Horner: u = x; for i = K..1: u = x + (A u)/i   (bf16 state)
    const int db = (N + 15) / 16;
    const uint4v* Xv = (const uint4v*)Xb;
    uint4v* U0v = (uint4v*)U0;
    uint4v* U1v = (uint4v*)U1;
    horner_bf_kernel<<<db, 256, 0, stream>>>(Xv, Xv, U0v, row_start, degv, ssrc, 1.0f / 6.0f, N);
    horner_bf_kernel<<<db, 256, 0, stream>>>(U0v, Xv, U1v, row_start, degv, ssrc, 1.0f / 5.0f, N);
    horner_bf_kernel<<<db, 256, 0, stream>>>(U1v, Xv, U0v, row_start, degv, ssrc, 1.0f / 4.0f, N);
    horner_bf_kernel<<<db, 256, 0, stream>>>(U0v, Xv, U1v, row_start, degv, ssrc, 1.0f / 3.0f, N);
    horner_bf_kernel<<<db, 256, 0, stream>>>(U1v, Xv, U0v, row_start, degv, ssrc, 1.0f / 2.0f, N);
    horner_bf_kernel<<<db, 256, 0, stream>>>(U0v, Xv, U1v, row_start, degv, ssrc, 1.0f, N);
    // final diffusion result: U1 (bf16)

    // out = silu(U1 @ W1 + b1) @ W2 + b2   (fused, x2 stays in LDS)
    gemm23_fused_kernel<<<gb, 256, 0, stream>>>(U1, Wt + 16384, b1,
                                                Wt + 2 * 16384, b2, out, N);
}